// Round 7
// baseline (405.631 us; speedup 1.0000x reference)
//
#include <hip/hip_runtime.h>
#include <hip/hip_bf16.h>
#include <stdint.h>

#define S_LEN 2048
#define HID_DIM 2048
#define HQ 32
#define HKV 8
#define NPROJ 5120   // 2048 q | 512 k | 512 v | 2048 g
// Q pre-scale: attention scale * log2(e), so softmax runs in base-2 (v_exp_f32 native)
#define QSCALE_LOG2 (0.125f * 1.44269504088896f)

using f32x4 = __attribute__((ext_vector_type(4))) float;
using bfrag = __attribute__((ext_vector_type(8))) short;

__device__ __forceinline__ unsigned short f2bf(float f) {
    union { float f; unsigned u; } a; a.f = f;
    unsigned r = a.u + 0x7fffu + ((a.u >> 16) & 1u);
    return (unsigned short)(r >> 16);
}
__device__ __forceinline__ float bf2f(unsigned short h) {
    union { unsigned u; float f; } a; a.u = ((unsigned)h) << 16;
    return a.f;
}

// async global->LDS, 16B per lane; LDS dest must be wave-uniform base (+lane*16 implicit)
__device__ __forceinline__ void gload16(const void* g, void* l) {
    __builtin_amdgcn_global_load_lds((const __attribute__((address_space(1))) unsigned int*)g,
                                     (__attribute__((address_space(3))) unsigned int*)l, 16, 0, 0);
}

// ---------------- x fp32 -> bf16 ----------------
__global__ void k_convert_x(const float* __restrict__ x, unsigned short* __restrict__ xb, int n4) {
    int i = blockIdx.x * blockDim.x + threadIdx.x;
    if (i < n4) {
        float4 v = ((const float4*)x)[i];
        ushort4 o;
        o.x = f2bf(v.x); o.y = f2bf(v.y); o.z = f2bf(v.z); o.w = f2bf(v.w);
        ((ushort4*)xb)[i] = o;
    }
}

// ---------------- W [K][N] fp32 -> Wt bf16 [N][K] (at row offset) ----------------
__global__ void k_transpose_w(const float* __restrict__ src, unsigned short* __restrict__ dst,
                              int K, int N, int rowOff) {
    __shared__ float tile[32][33];
    int n0 = blockIdx.x * 32;
    int k0 = blockIdx.y * 32;
    int lx = threadIdx.x & 31;
    int ly = threadIdx.x >> 5;  // 0..7
#pragma unroll
    for (int i = 0; i < 4; i++) {
        int r = ly + i * 8;
        tile[r][lx] = src[(size_t)(k0 + r) * N + n0 + lx];
    }
    __syncthreads();
#pragma unroll
    for (int i = 0; i < 4; i++) {
        int nn = ly + i * 8;
        dst[(size_t)(rowOff + n0 + nn) * K + k0 + lx] = f2bf(tile[lx][nn]);
    }
}

// ---------------- generic bf16 GEMM (m97 structure): A[M][K] x Bt[N][K] -> C[M][N] fp32 ----------------
__global__ __launch_bounds__(256) void k_gemm_bf16(
        const unsigned short* __restrict__ A,
        const unsigned short* __restrict__ Bt,
        float* __restrict__ C,
        int M, int N, int K) {
    __shared__ __align__(16) unsigned short As[128 * 64];
    __shared__ __align__(16) unsigned short Bs[128 * 64];
    const int tid = threadIdx.x;
    const int lane = tid & 63;
    const int w = tid >> 6;
    const int wm = (w >> 1) * 64, wn = (w & 1) * 64;
    const int bm0 = blockIdx.y * 128, bn0 = blockIdx.x * 128;
    const int lr = lane & 15;
    const int lk = (lane >> 4) * 8;
    const int srow_in = lane >> 3;
    const int scol = (lane & 7) * 8;

    f32x4 acc[4][4] = {};

    for (int k0 = 0; k0 < K; k0 += 64) {
        __syncthreads();
#pragma unroll
        for (int p = 0; p < 4; p++) {
            int chunk = p * 4 + w;
            int row = chunk * 8 + srow_in;
            gload16(&A[(size_t)(bm0 + row) * K + k0 + scol], &As[chunk * 512]);
            gload16(&Bt[(size_t)(bn0 + row) * K + k0 + scol], &Bs[chunk * 512]);
        }
        __syncthreads();
#pragma unroll
        for (int kc = 0; kc < 2; kc++) {
            bfrag af[4], bfr[4];
#pragma unroll
            for (int t = 0; t < 4; t++)
                af[t] = *(const bfrag*)&As[(wm + t * 16 + lr) * 64 + kc * 32 + lk];
#pragma unroll
            for (int t = 0; t < 4; t++)
                bfr[t] = *(const bfrag*)&Bs[(wn + t * 16 + lr) * 64 + kc * 32 + lk];
#pragma unroll
            for (int mt = 0; mt < 4; mt++)
#pragma unroll
                for (int nt = 0; nt < 4; nt++)
                    acc[mt][nt] = __builtin_amdgcn_mfma_f32_16x16x32_bf16(af[mt], bfr[nt], acc[mt][nt], 0, 0, 0);
        }
    }
    const int orow = (lane >> 4) * 4;
#pragma unroll
    for (int mt = 0; mt < 4; mt++)
#pragma unroll
        for (int nt = 0; nt < 4; nt++)
#pragma unroll
            for (int j = 0; j < 4; j++)
                C[(size_t)(bm0 + wm + mt * 16 + orow + j) * N + bn0 + wn + nt * 16 + lr] = acc[mt][nt][j];
}

// ---------------- projection GEMM with FUSED epilogue (RoPE / v-transpose / sigmoid gate) ----------------
// Same core as k_gemm_bf16 (M=2048, N=5120, K=2048). Region is uniform per block-col:
//   bcol 0..15 = q (RoPE, pre-scaled bf16) | 16..19 = k (RoPE, bf16 + fp32 out)
//   | 20..23 = v (transposed bf16 + fp32 out) | 24..39 = gate (sigmoid bf16)
// RoPE partner (d +/- 32) lives in the SAME thread's acc at nt^2.
__global__ __launch_bounds__(256) void k_gemm_proj(
        const unsigned short* __restrict__ A,
        const unsigned short* __restrict__ Bt,
        const float* __restrict__ rc, const float* __restrict__ rs,
        const float* __restrict__ bg,
        unsigned short* __restrict__ qb,    // [HQ][S][64]
        unsigned short* __restrict__ kbuf,  // [HKV][S][64]
        unsigned short* __restrict__ vt,    // [HKV][64][S]
        unsigned short* __restrict__ alpha, // [S][2048]
        float* __restrict__ outk, float* __restrict__ outv) {
    __shared__ __align__(16) unsigned short As[128 * 64];
    __shared__ __align__(16) unsigned short Bs[128 * 64];
    const int tid = threadIdx.x;
    const int lane = tid & 63;
    const int w = tid >> 6;
    const int wm = (w >> 1) * 64, wn = (w & 1) * 64;
    const int bcol = blockIdx.x;
    const int bm0 = blockIdx.y * 128, bn0 = bcol * 128;
    const int lr = lane & 15;
    const int lk = (lane >> 4) * 8;
    const int srow_in = lane >> 3;
    const int scol = (lane & 7) * 8;
    const int K = HID_DIM;

    f32x4 acc[4][4] = {};

    for (int k0 = 0; k0 < K; k0 += 64) {
        __syncthreads();
#pragma unroll
        for (int p = 0; p < 4; p++) {
            int chunk = p * 4 + w;
            int row = chunk * 8 + srow_in;
            gload16(&A[(size_t)(bm0 + row) * K + k0 + scol], &As[chunk * 512]);
            gload16(&Bt[(size_t)(bn0 + row) * K + k0 + scol], &Bs[chunk * 512]);
        }
        __syncthreads();
#pragma unroll
        for (int kc = 0; kc < 2; kc++) {
            bfrag af[4], bfr[4];
#pragma unroll
            for (int t = 0; t < 4; t++)
                af[t] = *(const bfrag*)&As[(wm + t * 16 + lr) * 64 + kc * 32 + lk];
#pragma unroll
            for (int t = 0; t < 4; t++)
                bfr[t] = *(const bfrag*)&Bs[(wn + t * 16 + lr) * 64 + kc * 32 + lk];
#pragma unroll
            for (int mt = 0; mt < 4; mt++)
#pragma unroll
                for (int nt = 0; nt < 4; nt++)
                    acc[mt][nt] = __builtin_amdgcn_mfma_f32_16x16x32_bf16(af[mt], bfr[nt], acc[mt][nt], 0, 0, 0);
        }
    }

    const int orow = (lane >> 4) * 4;
    if (bcol < 20) {
        // q or k: RoPE in-register. d = (wn+nt*16+lr)&63; d<32 <=> nt<2; partner at nt^2.
        const bool isq = (bcol < 16);
#pragma unroll
        for (int mt = 0; mt < 4; mt++)
#pragma unroll
            for (int j = 0; j < 4; j++) {
                const int s = bm0 + wm + mt * 16 + orow + j;
#pragma unroll
                for (int nt = 0; nt < 4; nt++) {
                    const int n = bn0 + wn + nt * 16 + lr;
                    const int d = n & 63;
                    const float c = rc[(s << 6) + d];
                    const float sn = rs[(s << 6) + d];
                    const float val = acc[mt][nt][j];
                    const float partner = acc[mt][nt ^ 2][j];
                    const float rot = (nt < 2) ? -partner : partner;
                    const float o = val * c + rot * sn;
                    if (isq) {
                        const int h = n >> 6;
                        qb[((size_t)h * S_LEN + s) * 64 + d] = f2bf(o * QSCALE_LOG2);
                    } else {
                        const int h = (n - 2048) >> 6;
                        const size_t oidx = ((size_t)h * S_LEN + s) * 64 + d;
                        kbuf[oidx] = f2bf(o);
                        outk[oidx] = o;
                    }
                }
            }
    } else if (bcol < 24) {
        // v: transposed bf16 + fp32 out
#pragma unroll
        for (int mt = 0; mt < 4; mt++)
#pragma unroll
            for (int j = 0; j < 4; j++) {
                const int s = bm0 + wm + mt * 16 + orow + j;
#pragma unroll
                for (int nt = 0; nt < 4; nt++) {
                    const int n = bn0 + wn + nt * 16 + lr;
                    const int h = (n - 2560) >> 6;
                    const int d = n & 63;
                    const float val = acc[mt][nt][j];
                    vt[((size_t)h * 64 + d) * S_LEN + s] = f2bf(val);
                    outv[((size_t)h * S_LEN + s) * 64 + d] = val;
                }
            }
    } else {
        // gate: sigmoid(val + bg)
#pragma unroll
        for (int mt = 0; mt < 4; mt++)
#pragma unroll
            for (int j = 0; j < 4; j++) {
                const int s = bm0 + wm + mt * 16 + orow + j;
#pragma unroll
                for (int nt = 0; nt < 4; nt++) {
                    const int n = bn0 + wn + nt * 16 + lr;
                    const int m = n - 3072;
                    const float a = 1.0f / (1.0f + __expf(-(acc[mt][nt][j] + bg[m])));
                    alpha[(size_t)s * 2048 + m] = f2bf(a);
                }
            }
    }
}

// ---------------- flash attention (causal, GQA) + FUSED GroupNorm*gate ----------------
// 2-phase pipelined: double-buffered K/V LDS via async global_load_lds (linear dest,
// pre-swizzled global source; same XOR on ds_read side -> 2-way banks = free).
// Block = 64 q-rows x 1 head, 4 waves x 16 rows. One barrier per KV tile.
// Epilogue: each row's 64-dim group is 16 lanes x 4 frags -> shfl_xor mean/var,
// normalize, multiply by gate, write gno bf16 directly.
__global__ __launch_bounds__(256) void k_attn(
        const unsigned short* __restrict__ qb,
        const unsigned short* __restrict__ kbuf,
        const unsigned short* __restrict__ vt,
        const unsigned short* __restrict__ alpha,
        const float* __restrict__ gnw, const float* __restrict__ gnb,
        unsigned short* __restrict__ gno) {  // [S][2048]
    __shared__ __align__(16) unsigned short Ks[2][64 * 64];
    __shared__ __align__(16) unsigned short Vs[2][64 * 64];
    __shared__ __align__(16) unsigned short Ps[4][16 * 72];
    const int tid = threadIdx.x;
    const int lane = tid & 63;
    const int w = tid >> 6;
    const int lr = lane & 15;
    const int lg = lane >> 4;
    const int lk = lg * 8;

    const int bid = blockIdx.x;
    const int qblk = 31 - (bid >> 5);        // heavy blocks dispatched first
    const int h = bid & 31;
    const int hk = h >> 2;
    const int r0 = qblk * 64 + w * 16;

    // swizzled LDS read offsets (ushort units)
    const int swzkey = (lr & 7) << 4;
    const int swz0 = ((lg * 16) ^ swzkey) >> 1;
    const int swz1 = ((64 + lg * 16) ^ swzkey) >> 1;
    // staging: pre-swizzled global source col so linear LDS + swizzled read = identity
    const int srow = lane >> 3;
    const int scol = (((lane & 7) ^ srow) << 3);

    const unsigned short* Kg = &kbuf[(size_t)hk * S_LEN * 64];
    const unsigned short* Vg = &vt[(size_t)hk * 64 * S_LEN];

    bfrag qf[2];
    {
        const unsigned short* qrow = &qb[((size_t)h * S_LEN + r0 + lr) * 64];
        qf[0] = *(const bfrag*)&qrow[lk];
        qf[1] = *(const bfrag*)&qrow[32 + lk];
    }

    float m_r[4], l_r[4];
    f32x4 o_acc[4] = {};
#pragma unroll
    for (int j = 0; j < 4; j++) { m_r[j] = -1e30f; l_r[j] = 0.0f; }

#define STAGE(buf, kb)                                                                  \
    {                                                                                   \
        _Pragma("unroll")                                                               \
        for (int c = 0; c < 2; c++) {                                                   \
            int chunk = w * 2 + c;                                                      \
            gload16(&Kg[(size_t)((kb) * 64 + chunk * 8 + srow) * 64 + scol],            \
                    &Ks[buf][chunk * 512]);                                             \
            gload16(&Vg[(size_t)(chunk * 8 + srow) * S_LEN + (kb) * 64 + scol],         \
                    &Vs[buf][chunk * 512]);                                             \
        }                                                                               \
    }

    const int nt = qblk + 1;
    STAGE(0, 0);
    __syncthreads();
    int cur = 0;

    for (int kb = 0; kb < nt; kb++) {
        if (kb + 1 < nt) STAGE(cur ^ 1, kb + 1);
        const unsigned short* Kc = Ks[cur];
        const unsigned short* Vc = Vs[cur];
        // ---- QK^T ----
        f32x4 sacc[4] = {};
        __builtin_amdgcn_s_setprio(1);
#pragma unroll
        for (int g = 0; g < 4; g++) {
            bfrag kf0 = *(const bfrag*)&Kc[g * 1024 + lr * 64 + swz0];
            bfrag kf1 = *(const bfrag*)&Kc[g * 1024 + lr * 64 + swz1];
            sacc[g] = __builtin_amdgcn_mfma_f32_16x16x32_bf16(qf[0], kf0, sacc[g], 0, 0, 0);
            sacc[g] = __builtin_amdgcn_mfma_f32_16x16x32_bf16(qf[1], kf1, sacc[g], 0, 0, 0);
        }
        __builtin_amdgcn_s_setprio(0);
        if (kb == qblk) {
#pragma unroll
            for (int g = 0; g < 4; g++)
#pragma unroll
                for (int j = 0; j < 4; j++) {
                    int col = kb * 64 + g * 16 + lr;
                    int row = r0 + lg * 4 + j;
                    if (col > row) sacc[g][j] = -1e30f;
                }
        }
        // ---- online softmax (base-2) ----
        float ps[4];
#pragma unroll
        for (int j = 0; j < 4; j++) {
            float tv = fmaxf(fmaxf(sacc[0][j], sacc[1][j]), fmaxf(sacc[2][j], sacc[3][j]));
#pragma unroll
            for (int msk = 1; msk < 16; msk <<= 1)
                tv = fmaxf(tv, __shfl_xor(tv, msk, 64));
            float mnew = fmaxf(m_r[j], tv);
            float sc = exp2f(m_r[j] - mnew);
            m_r[j] = mnew;
            l_r[j] *= sc;
#pragma unroll
            for (int g = 0; g < 4; g++) o_acc[g][j] *= sc;
            ps[j] = 0.0f;
        }
#pragma unroll
        for (int g = 0; g < 4; g++)
#pragma unroll
            for (int j = 0; j < 4; j++) {
                float p = exp2f(sacc[g][j] - m_r[j]);
                ps[j] += p;
                Ps[w][(lg * 4 + j) * 72 + g * 16 + lr] = f2bf(p);
            }
#pragma unroll
        for (int j = 0; j < 4; j++) {
            float pv = ps[j];
#pragma unroll
            for (int msk = 1; msk < 16; msk <<= 1)
                pv += __shfl_xor(pv, msk, 64);
            l_r[j] += pv;
        }
        bfrag pf0 = *(const bfrag*)&Ps[w][lr * 72 + lk];
        bfrag pf1 = *(const bfrag*)&Ps[w][lr * 72 + 32 + lk];
        // ---- PV ----
        __builtin_amdgcn_s_setprio(1);
#pragma unroll
        for (int g = 0; g < 4; g++) {
            bfrag vf0 = *(const bfrag*)&Vc[g * 1024 + lr * 64 + swz0];
            bfrag vf1 = *(const bfrag*)&Vc[g * 1024 + lr * 64 + swz1];
            o_acc[g] = __builtin_amdgcn_mfma_f32_16x16x32_bf16(pf0, vf0, o_acc[g], 0, 0, 0);
            o_acc[g] = __builtin_amdgcn_mfma_f32_16x16x32_bf16(pf1, vf1, o_acc[g], 0, 0, 0);
        }
        __builtin_amdgcn_s_setprio(0);
        __syncthreads();
        cur ^= 1;
    }
#undef STAGE

    // ---- fused GroupNorm(D=64) * gate ----
    float gv[4][4];
#pragma unroll
    for (int j = 0; j < 4; j++) {
        const float inv = 1.0f / (l_r[j] + 1e-9f);
#pragma unroll
        for (int g = 0; g < 4; g++) gv[g][j] = o_acc[g][j] * inv;
    }
#pragma unroll
    for (int j = 0; j < 4; j++) {
        float sum = gv[0][j] + gv[1][j] + gv[2][j] + gv[3][j];
#pragma unroll
        for (int msk = 1; msk < 16; msk <<= 1) sum += __shfl_xor(sum, msk, 64);
        const float mu = sum * (1.0f / 64.0f);
        float vs = 0.0f;
#pragma unroll
        for (int g = 0; g < 4; g++) { float dd = gv[g][j] - mu; vs += dd * dd; }
#pragma unroll
        for (int msk = 1; msk < 16; msk <<= 1) vs += __shfl_xor(vs, msk, 64);
        const float rstd = rsqrtf(vs * (1.0f / 64.0f) + 1e-5f);
        const int s = r0 + lg * 4 + j;
#pragma unroll
        for (int g = 0; g < 4; g++) {
            const int col = (h << 6) + g * 16 + lr;
            const float gn = (gv[g][j] - mu) * rstd * gnw[col] + gnb[col];
            const float a = bf2f(alpha[(size_t)s * 2048 + col]);
            gno[(size_t)s * 2048 + col] = f2bf(gn * a);
        }
    }
}

extern "C" void kernel_launch(void* const* d_in, const int* in_sizes, int n_in,
                              void* d_out, int out_size, void* d_ws, size_t ws_size,
                              hipStream_t stream) {
    const float* x   = (const float*)d_in[0];
    const float* rc  = (const float*)d_in[1];
    const float* rs  = (const float*)d_in[2];
    const float* Wq  = (const float*)d_in[3];
    const float* Wk  = (const float*)d_in[4];
    const float* Wv  = (const float*)d_in[5];
    const float* Wo  = (const float*)d_in[6];
    const float* Wg  = (const float*)d_in[7];
    const float* bg  = (const float*)d_in[8];
    const float* gnw = (const float*)d_in[9];
    const float* gnb = (const float*)d_in[10];
    float* out = (float*)d_out;

    char* ws = (char*)d_ws;
    unsigned short* xb    = (unsigned short*)(ws);                      // 8 MB
    unsigned short* WcatT = (unsigned short*)(ws + 8388608);            // 20 MB (weights, live through proj GEMM)
    unsigned short* WoT   = (unsigned short*)(ws + 29360128);           // 8 MB
    unsigned short* alpha = (unsigned short*)(ws + 37748736);           // 8 MB
    unsigned short* qb    = (unsigned short*)(ws + 46137344);           // 8 MB
    unsigned short* kbuf  = (unsigned short*)(ws + 54525952);           // 2 MB
    unsigned short* vt    = (unsigned short*)(ws + 56623104);           // 2 MB
    unsigned short* gno   = (unsigned short*)(ws + 58720256);           // 8 MB

    hipLaunchKernelGGL(k_convert_x, dim3(4096), dim3(256), 0, stream, x, xb, 2048 * 2048 / 4);
    hipLaunchKernelGGL(k_transpose_w, dim3(64, 64), dim3(256), 0, stream, Wq, WcatT, 2048, 2048, 0);
    hipLaunchKernelGGL(k_transpose_w, dim3(16, 64), dim3(256), 0, stream, Wk, WcatT, 2048, 512, 2048);
    hipLaunchKernelGGL(k_transpose_w, dim3(16, 64), dim3(256), 0, stream, Wv, WcatT, 2048, 512, 2560);
    hipLaunchKernelGGL(k_transpose_w, dim3(64, 64), dim3(256), 0, stream, Wg, WcatT, 2048, 2048, 3072);
    hipLaunchKernelGGL(k_transpose_w, dim3(64, 64), dim3(256), 0, stream, Wo, WoT, 2048, 2048, 0);

    float* outk = out + (size_t)4 * 1024 * 1024;
    float* outv = out + (size_t)5 * 1024 * 1024;

    hipLaunchKernelGGL(k_gemm_proj, dim3(5120 / 128, 2048 / 128), dim3(256), 0, stream,
                       xb, WcatT, rc, rs, bg, qb, kbuf, vt, alpha, outk, outv);

    hipLaunchKernelGGL(k_attn, dim3(1024), dim3(256), 0, stream,
                       qb, kbuf, vt, alpha, gnw, gnb, gno);

    hipLaunchKernelGGL(k_gemm_bf16, dim3(2048 / 128, 2048 / 128), dim3(256), 0, stream,
                       gno, WoT, out, 2048, 2048, 2048);
}

// Round 8
// 328.491 us; speedup vs baseline: 1.2348x; 1.2348x over previous
//
#include <hip/hip_runtime.h>
#include <hip/hip_bf16.h>
#include <stdint.h>

#define S_LEN 2048
#define HID_DIM 2048
#define HQ 32
#define HKV 8
#define NPROJ 5120   // 2048 q | 512 k | 512 v | 2048 g
// Q pre-scale: attention scale * log2(e), so softmax runs in base-2 (v_exp_f32 native)
#define QSCALE_LOG2 (0.125f * 1.44269504088896f)

using f32x4 = __attribute__((ext_vector_type(4))) float;
using bfrag = __attribute__((ext_vector_type(8))) short;

__device__ __forceinline__ unsigned short f2bf(float f) {
    union { float f; unsigned u; } a; a.f = f;
    unsigned r = a.u + 0x7fffu + ((a.u >> 16) & 1u);
    return (unsigned short)(r >> 16);
}
__device__ __forceinline__ float bf2f(unsigned short h) {
    union { unsigned u; float f; } a; a.u = ((unsigned)h) << 16;
    return a.f;
}

// async global->LDS, 16B per lane; LDS dest must be wave-uniform base (+lane*16 implicit)
__device__ __forceinline__ void gload16(const void* g, void* l) {
    __builtin_amdgcn_global_load_lds((const __attribute__((address_space(1))) unsigned int*)g,
                                     (__attribute__((address_space(3))) unsigned int*)l, 16, 0, 0);
}

// ---------------- x fp32 -> bf16 ----------------
__global__ void k_convert_x(const float* __restrict__ x, unsigned short* __restrict__ xb, int n4) {
    int i = blockIdx.x * blockDim.x + threadIdx.x;
    if (i < n4) {
        float4 v = ((const float4*)x)[i];
        ushort4 o;
        o.x = f2bf(v.x); o.y = f2bf(v.y); o.z = f2bf(v.z); o.w = f2bf(v.w);
        ((ushort4*)xb)[i] = o;
    }
}

// ---------------- W [K][N] fp32 -> Wt bf16 [N][K] (at row offset) ----------------
__global__ void k_transpose_w(const float* __restrict__ src, unsigned short* __restrict__ dst,
                              int K, int N, int rowOff) {
    __shared__ float tile[32][33];
    int n0 = blockIdx.x * 32;
    int k0 = blockIdx.y * 32;
    int lx = threadIdx.x & 31;
    int ly = threadIdx.x >> 5;  // 0..7
#pragma unroll
    for (int i = 0; i < 4; i++) {
        int r = ly + i * 8;
        tile[r][lx] = src[(size_t)(k0 + r) * N + n0 + lx];
    }
    __syncthreads();
#pragma unroll
    for (int i = 0; i < 4; i++) {
        int nn = ly + i * 8;
        dst[(size_t)(rowOff + n0 + nn) * K + k0 + lx] = f2bf(tile[lx][nn]);
    }
}

// ---------------- generic bf16 GEMM (m97 structure): A[M][K] x Bt[N][K] -> C[M][N] fp32 ----------------
__global__ __launch_bounds__(256) void k_gemm_bf16(
        const unsigned short* __restrict__ A,
        const unsigned short* __restrict__ Bt,
        float* __restrict__ C,
        int M, int N, int K) {
    __shared__ __align__(16) unsigned short As[128 * 64];
    __shared__ __align__(16) unsigned short Bs[128 * 64];
    const int tid = threadIdx.x;
    const int lane = tid & 63;
    const int w = tid >> 6;
    const int wm = (w >> 1) * 64, wn = (w & 1) * 64;
    const int bm0 = blockIdx.y * 128, bn0 = blockIdx.x * 128;
    const int lr = lane & 15;
    const int lk = (lane >> 4) * 8;
    const int srow_in = lane >> 3;
    const int scol = (lane & 7) * 8;

    f32x4 acc[4][4] = {};

    for (int k0 = 0; k0 < K; k0 += 64) {
        __syncthreads();
#pragma unroll
        for (int p = 0; p < 4; p++) {
            int chunk = p * 4 + w;
            int row = chunk * 8 + srow_in;
            gload16(&A[(size_t)(bm0 + row) * K + k0 + scol], &As[chunk * 512]);
            gload16(&Bt[(size_t)(bn0 + row) * K + k0 + scol], &Bs[chunk * 512]);
        }
        __syncthreads();
#pragma unroll
        for (int kc = 0; kc < 2; kc++) {
            bfrag af[4], bfr[4];
#pragma unroll
            for (int t = 0; t < 4; t++)
                af[t] = *(const bfrag*)&As[(wm + t * 16 + lr) * 64 + kc * 32 + lk];
#pragma unroll
            for (int t = 0; t < 4; t++)
                bfr[t] = *(const bfrag*)&Bs[(wn + t * 16 + lr) * 64 + kc * 32 + lk];
#pragma unroll
            for (int mt = 0; mt < 4; mt++)
#pragma unroll
                for (int nt = 0; nt < 4; nt++)
                    acc[mt][nt] = __builtin_amdgcn_mfma_f32_16x16x32_bf16(af[mt], bfr[nt], acc[mt][nt], 0, 0, 0);
        }
    }
    const int orow = (lane >> 4) * 4;
#pragma unroll
    for (int mt = 0; mt < 4; mt++)
#pragma unroll
        for (int nt = 0; nt < 4; nt++)
#pragma unroll
            for (int j = 0; j < 4; j++)
                C[(size_t)(bm0 + wm + mt * 16 + orow + j) * N + bn0 + wn + nt * 16 + lr] = acc[mt][nt][j];
}

// ---------------- projection GEMM with FUSED epilogue (RoPE / v-transpose / sigmoid gate) ----------------
// Same core as k_gemm_bf16 (M=2048, N=5120, K=2048). Region is uniform per block-col:
//   bcol 0..15 = q (RoPE, pre-scaled bf16) | 16..19 = k (RoPE, bf16 + fp32 out)
//   | 20..23 = v (transposed bf16 + fp32 out) | 24..39 = gate (sigmoid bf16)
// RoPE partner (d +/- 32) lives in the SAME thread's acc at nt^2.
// __launch_bounds__(256, 4): cap VGPR at 128 (R7 post-mortem: unconstrained alloc hit
// 140 VGPR -> 2 waves/SIMD occupancy cliff, MfmaUtil 17->10.5. Epilogue spills are
// once-per-kernel; the K-loop needs the 4-waves/SIMD latency hiding.)
__global__ __launch_bounds__(256, 4) void k_gemm_proj(
        const unsigned short* __restrict__ A,
        const unsigned short* __restrict__ Bt,
        const float* __restrict__ rc, const float* __restrict__ rs,
        const float* __restrict__ bg,
        unsigned short* __restrict__ qb,    // [HQ][S][64]
        unsigned short* __restrict__ kbuf,  // [HKV][S][64]
        unsigned short* __restrict__ vt,    // [HKV][64][S]
        unsigned short* __restrict__ alpha, // [S][2048]
        float* __restrict__ outk, float* __restrict__ outv) {
    __shared__ __align__(16) unsigned short As[128 * 64];
    __shared__ __align__(16) unsigned short Bs[128 * 64];
    const int tid = threadIdx.x;
    const int lane = tid & 63;
    const int w = tid >> 6;
    const int wm = (w >> 1) * 64, wn = (w & 1) * 64;
    const int bcol = blockIdx.x;
    const int bm0 = blockIdx.y * 128, bn0 = bcol * 128;
    const int lr = lane & 15;
    const int lk = (lane >> 4) * 8;
    const int srow_in = lane >> 3;
    const int scol = (lane & 7) * 8;
    const int K = HID_DIM;

    f32x4 acc[4][4] = {};

    for (int k0 = 0; k0 < K; k0 += 64) {
        __syncthreads();
#pragma unroll
        for (int p = 0; p < 4; p++) {
            int chunk = p * 4 + w;
            int row = chunk * 8 + srow_in;
            gload16(&A[(size_t)(bm0 + row) * K + k0 + scol], &As[chunk * 512]);
            gload16(&Bt[(size_t)(bn0 + row) * K + k0 + scol], &Bs[chunk * 512]);
        }
        __syncthreads();
#pragma unroll
        for (int kc = 0; kc < 2; kc++) {
            bfrag af[4], bfr[4];
#pragma unroll
            for (int t = 0; t < 4; t++)
                af[t] = *(const bfrag*)&As[(wm + t * 16 + lr) * 64 + kc * 32 + lk];
#pragma unroll
            for (int t = 0; t < 4; t++)
                bfr[t] = *(const bfrag*)&Bs[(wn + t * 16 + lr) * 64 + kc * 32 + lk];
#pragma unroll
            for (int mt = 0; mt < 4; mt++)
#pragma unroll
                for (int nt = 0; nt < 4; nt++)
                    acc[mt][nt] = __builtin_amdgcn_mfma_f32_16x16x32_bf16(af[mt], bfr[nt], acc[mt][nt], 0, 0, 0);
        }
    }

    const int orow = (lane >> 4) * 4;
    if (bcol < 20) {
        // q or k: RoPE in-register. d = (wn+nt*16+lr)&63; d<32 <=> nt<2; partner at nt^2.
        const bool isq = (bcol < 16);
#pragma unroll
        for (int mt = 0; mt < 4; mt++)
#pragma unroll
            for (int j = 0; j < 4; j++) {
                const int s = bm0 + wm + mt * 16 + orow + j;
#pragma unroll
                for (int nt = 0; nt < 4; nt++) {
                    const int n = bn0 + wn + nt * 16 + lr;
                    const int d = n & 63;
                    const float c = rc[(s << 6) + d];
                    const float sn = rs[(s << 6) + d];
                    const float val = acc[mt][nt][j];
                    const float partner = acc[mt][nt ^ 2][j];
                    const float rot = (nt < 2) ? -partner : partner;
                    const float o = val * c + rot * sn;
                    if (isq) {
                        const int h = n >> 6;
                        qb[((size_t)h * S_LEN + s) * 64 + d] = f2bf(o * QSCALE_LOG2);
                    } else {
                        const int h = (n - 2048) >> 6;
                        const size_t oidx = ((size_t)h * S_LEN + s) * 64 + d;
                        kbuf[oidx] = f2bf(o);
                        outk[oidx] = o;
                    }
                }
            }
    } else if (bcol < 24) {
        // v: transposed bf16 + fp32 out
#pragma unroll
        for (int mt = 0; mt < 4; mt++)
#pragma unroll
            for (int j = 0; j < 4; j++) {
                const int s = bm0 + wm + mt * 16 + orow + j;
#pragma unroll
                for (int nt = 0; nt < 4; nt++) {
                    const int n = bn0 + wn + nt * 16 + lr;
                    const int h = (n - 2560) >> 6;
                    const int d = n & 63;
                    const float val = acc[mt][nt][j];
                    vt[((size_t)h * 64 + d) * S_LEN + s] = f2bf(val);
                    outv[((size_t)h * S_LEN + s) * 64 + d] = val;
                }
            }
    } else {
        // gate: sigmoid(val + bg)
#pragma unroll
        for (int mt = 0; mt < 4; mt++)
#pragma unroll
            for (int j = 0; j < 4; j++) {
                const int s = bm0 + wm + mt * 16 + orow + j;
#pragma unroll
                for (int nt = 0; nt < 4; nt++) {
                    const int n = bn0 + wn + nt * 16 + lr;
                    const int m = n - 3072;
                    const float a = 1.0f / (1.0f + __expf(-(acc[mt][nt][j] + bg[m])));
                    alpha[(size_t)s * 2048 + m] = f2bf(a);
                }
            }
    }
}

// ---------------- flash attention (causal, GQA) + FUSED GroupNorm*gate ----------------
// 2-phase pipelined: double-buffered K/V LDS via async global_load_lds (linear dest,
// pre-swizzled global source; same XOR on ds_read side -> 2-way banks = free).
// Block = 64 q-rows x 1 head, 4 waves x 16 rows. One barrier per KV tile.
// Epilogue: each row's 64-dim group is 16 lanes x 4 frags -> shfl_xor mean/var,
// normalize, multiply by gate, write gno bf16 directly.
__global__ __launch_bounds__(256) void k_attn(
        const unsigned short* __restrict__ qb,
        const unsigned short* __restrict__ kbuf,
        const unsigned short* __restrict__ vt,
        const unsigned short* __restrict__ alpha,
        const float* __restrict__ gnw, const float* __restrict__ gnb,
        unsigned short* __restrict__ gno) {  // [S][2048]
    __shared__ __align__(16) unsigned short Ks[2][64 * 64];
    __shared__ __align__(16) unsigned short Vs[2][64 * 64];
    __shared__ __align__(16) unsigned short Ps[4][16 * 72];
    const int tid = threadIdx.x;
    const int lane = tid & 63;
    const int w = tid >> 6;
    const int lr = lane & 15;
    const int lg = lane >> 4;
    const int lk = lg * 8;

    const int bid = blockIdx.x;
    const int qblk = 31 - (bid >> 5);        // heavy blocks dispatched first
    const int h = bid & 31;
    const int hk = h >> 2;
    const int r0 = qblk * 64 + w * 16;

    // swizzled LDS read offsets (ushort units)
    const int swzkey = (lr & 7) << 4;
    const int swz0 = ((lg * 16) ^ swzkey) >> 1;
    const int swz1 = ((64 + lg * 16) ^ swzkey) >> 1;
    // staging: pre-swizzled global source col so linear LDS + swizzled read = identity
    const int srow = lane >> 3;
    const int scol = (((lane & 7) ^ srow) << 3);

    const unsigned short* Kg = &kbuf[(size_t)hk * S_LEN * 64];
    const unsigned short* Vg = &vt[(size_t)hk * 64 * S_LEN];

    bfrag qf[2];
    {
        const unsigned short* qrow = &qb[((size_t)h * S_LEN + r0 + lr) * 64];
        qf[0] = *(const bfrag*)&qrow[lk];
        qf[1] = *(const bfrag*)&qrow[32 + lk];
    }

    float m_r[4], l_r[4];
    f32x4 o_acc[4] = {};
#pragma unroll
    for (int j = 0; j < 4; j++) { m_r[j] = -1e30f; l_r[j] = 0.0f; }

#define STAGE(buf, kb)                                                                  \
    {                                                                                   \
        _Pragma("unroll")                                                               \
        for (int c = 0; c < 2; c++) {                                                   \
            int chunk = w * 2 + c;                                                      \
            gload16(&Kg[(size_t)((kb) * 64 + chunk * 8 + srow) * 64 + scol],            \
                    &Ks[buf][chunk * 512]);                                             \
            gload16(&Vg[(size_t)(chunk * 8 + srow) * S_LEN + (kb) * 64 + scol],         \
                    &Vs[buf][chunk * 512]);                                             \
        }                                                                               \
    }

    const int nt = qblk + 1;
    STAGE(0, 0);
    __syncthreads();
    int cur = 0;

    for (int kb = 0; kb < nt; kb++) {
        if (kb + 1 < nt) STAGE(cur ^ 1, kb + 1);
        const unsigned short* Kc = Ks[cur];
        const unsigned short* Vc = Vs[cur];
        // ---- QK^T ----
        f32x4 sacc[4] = {};
        __builtin_amdgcn_s_setprio(1);
#pragma unroll
        for (int g = 0; g < 4; g++) {
            bfrag kf0 = *(const bfrag*)&Kc[g * 1024 + lr * 64 + swz0];
            bfrag kf1 = *(const bfrag*)&Kc[g * 1024 + lr * 64 + swz1];
            sacc[g] = __builtin_amdgcn_mfma_f32_16x16x32_bf16(qf[0], kf0, sacc[g], 0, 0, 0);
            sacc[g] = __builtin_amdgcn_mfma_f32_16x16x32_bf16(qf[1], kf1, sacc[g], 0, 0, 0);
        }
        __builtin_amdgcn_s_setprio(0);
        if (kb == qblk) {
#pragma unroll
            for (int g = 0; g < 4; g++)
#pragma unroll
                for (int j = 0; j < 4; j++) {
                    int col = kb * 64 + g * 16 + lr;
                    int row = r0 + lg * 4 + j;
                    if (col > row) sacc[g][j] = -1e30f;
                }
        }
        // ---- online softmax (base-2) ----
        float ps[4];
#pragma unroll
        for (int j = 0; j < 4; j++) {
            float tv = fmaxf(fmaxf(sacc[0][j], sacc[1][j]), fmaxf(sacc[2][j], sacc[3][j]));
#pragma unroll
            for (int msk = 1; msk < 16; msk <<= 1)
                tv = fmaxf(tv, __shfl_xor(tv, msk, 64));
            float mnew = fmaxf(m_r[j], tv);
            float sc = exp2f(m_r[j] - mnew);
            m_r[j] = mnew;
            l_r[j] *= sc;
#pragma unroll
            for (int g = 0; g < 4; g++) o_acc[g][j] *= sc;
            ps[j] = 0.0f;
        }
#pragma unroll
        for (int g = 0; g < 4; g++)
#pragma unroll
            for (int j = 0; j < 4; j++) {
                float p = exp2f(sacc[g][j] - m_r[j]);
                ps[j] += p;
                Ps[w][(lg * 4 + j) * 72 + g * 16 + lr] = f2bf(p);
            }
#pragma unroll
        for (int j = 0; j < 4; j++) {
            float pv = ps[j];
#pragma unroll
            for (int msk = 1; msk < 16; msk <<= 1)
                pv += __shfl_xor(pv, msk, 64);
            l_r[j] += pv;
        }
        bfrag pf0 = *(const bfrag*)&Ps[w][lr * 72 + lk];
        bfrag pf1 = *(const bfrag*)&Ps[w][lr * 72 + 32 + lk];
        // ---- PV ----
        __builtin_amdgcn_s_setprio(1);
#pragma unroll
        for (int g = 0; g < 4; g++) {
            bfrag vf0 = *(const bfrag*)&Vc[g * 1024 + lr * 64 + swz0];
            bfrag vf1 = *(const bfrag*)&Vc[g * 1024 + lr * 64 + swz1];
            o_acc[g] = __builtin_amdgcn_mfma_f32_16x16x32_bf16(pf0, vf0, o_acc[g], 0, 0, 0);
            o_acc[g] = __builtin_amdgcn_mfma_f32_16x16x32_bf16(pf1, vf1, o_acc[g], 0, 0, 0);
        }
        __builtin_amdgcn_s_setprio(0);
        __syncthreads();
        cur ^= 1;
    }
#undef STAGE

    // ---- fused GroupNorm(D=64) * gate ----
    float gv[4][4];
#pragma unroll
    for (int j = 0; j < 4; j++) {
        const float inv = 1.0f / (l_r[j] + 1e-9f);
#pragma unroll
        for (int g = 0; g < 4; g++) gv[g][j] = o_acc[g][j] * inv;
    }
#pragma unroll
    for (int j = 0; j < 4; j++) {
        float sum = gv[0][j] + gv[1][j] + gv[2][j] + gv[3][j];
#pragma unroll
        for (int msk = 1; msk < 16; msk <<= 1) sum += __shfl_xor(sum, msk, 64);
        const float mu = sum * (1.0f / 64.0f);
        float vs = 0.0f;
#pragma unroll
        for (int g = 0; g < 4; g++) { float dd = gv[g][j] - mu; vs += dd * dd; }
#pragma unroll
        for (int msk = 1; msk < 16; msk <<= 1) vs += __shfl_xor(vs, msk, 64);
        const float rstd = rsqrtf(vs * (1.0f / 64.0f) + 1e-5f);
        const int s = r0 + lg * 4 + j;
#pragma unroll
        for (int g = 0; g < 4; g++) {
            const int col = (h << 6) + g * 16 + lr;
            const float gn = (gv[g][j] - mu) * rstd * gnw[col] + gnb[col];
            const float a = bf2f(alpha[(size_t)s * 2048 + col]);
            gno[(size_t)s * 2048 + col] = f2bf(gn * a);
        }
    }
}

extern "C" void kernel_launch(void* const* d_in, const int* in_sizes, int n_in,
                              void* d_out, int out_size, void* d_ws, size_t ws_size,
                              hipStream_t stream) {
    const float* x   = (const float*)d_in[0];
    const float* rc  = (const float*)d_in[1];
    const float* rs  = (const float*)d_in[2];
    const float* Wq  = (const float*)d_in[3];
    const float* Wk  = (const float*)d_in[4];
    const float* Wv  = (const float*)d_in[5];
    const float* Wo  = (const float*)d_in[6];
    const float* Wg  = (const float*)d_in[7];
    const float* bg  = (const float*)d_in[8];
    const float* gnw = (const float*)d_in[9];
    const float* gnb = (const float*)d_in[10];
    float* out = (float*)d_out;

    char* ws = (char*)d_ws;
    unsigned short* xb    = (unsigned short*)(ws);                      // 8 MB
    unsigned short* WcatT = (unsigned short*)(ws + 8388608);            // 20 MB (weights, live through proj GEMM)
    unsigned short* WoT   = (unsigned short*)(ws + 29360128);           // 8 MB
    unsigned short* alpha = (unsigned short*)(ws + 37748736);           // 8 MB
    unsigned short* qb    = (unsigned short*)(ws + 46137344);           // 8 MB
    unsigned short* kbuf  = (unsigned short*)(ws + 54525952);           // 2 MB
    unsigned short* vt    = (unsigned short*)(ws + 56623104);           // 2 MB
    unsigned short* gno   = (unsigned short*)(ws + 58720256);           // 8 MB

    hipLaunchKernelGGL(k_convert_x, dim3(4096), dim3(256), 0, stream, x, xb, 2048 * 2048 / 4);
    hipLaunchKernelGGL(k_transpose_w, dim3(64, 64), dim3(256), 0, stream, Wq, WcatT, 2048, 2048, 0);
    hipLaunchKernelGGL(k_transpose_w, dim3(16, 64), dim3(256), 0, stream, Wk, WcatT, 2048, 512, 2048);
    hipLaunchKernelGGL(k_transpose_w, dim3(16, 64), dim3(256), 0, stream, Wv, WcatT, 2048, 512, 2560);
    hipLaunchKernelGGL(k_transpose_w, dim3(64, 64), dim3(256), 0, stream, Wg, WcatT, 2048, 2048, 3072);
    hipLaunchKernelGGL(k_transpose_w, dim3(64, 64), dim3(256), 0, stream, Wo, WoT, 2048, 2048, 0);

    float* outk = out + (size_t)4 * 1024 * 1024;
    float* outv = out + (size_t)5 * 1024 * 1024;

    hipLaunchKernelGGL(k_gemm_proj, dim3(5120 / 128, 2048 / 128), dim3(256), 0, stream,
                       xb, WcatT, rc, rs, bg, qb, kbuf, vt, alpha, outk, outv);

    hipLaunchKernelGGL(k_attn, dim3(1024), dim3(256), 0, stream,
                       qb, kbuf, vt, alpha, gnw, gnb, gno);

    hipLaunchKernelGGL(k_gemm_bf16, dim3(2048 / 128, 2048 / 128), dim3(256), 0, stream,
                       gno, WoT, out, 2048, 2048, 2048);
}

// Round 11
// 308.992 us; speedup vs baseline: 1.3128x; 1.0631x over previous
//
#include <hip/hip_runtime.h>
#include <hip/hip_bf16.h>
#include <stdint.h>

#define S_LEN 2048
#define HID_DIM 2048
#define HQ 32
#define HKV 8
#define NPROJ 5120   // 2048 q | 512 k | 512 v | 2048 g
// Q pre-scale: attention scale * log2(e), so softmax runs in base-2 (v_exp_f32 native)
#define QSCALE_LOG2 (0.125f * 1.44269504088896f)

using f32x4 = __attribute__((ext_vector_type(4))) float;
using bfrag = __attribute__((ext_vector_type(8))) short;

__device__ __forceinline__ unsigned short f2bf(float f) {
    union { float f; unsigned u; } a; a.f = f;
    unsigned r = a.u + 0x7fffu + ((a.u >> 16) & 1u);
    return (unsigned short)(r >> 16);
}
__device__ __forceinline__ float bf2f(unsigned short h) {
    union { unsigned u; float f; } a; a.u = ((unsigned)h) << 16;
    return a.f;
}

// async global->LDS, 16B per lane; LDS dest must be wave-uniform base (+lane*16 implicit)
__device__ __forceinline__ void gload16(const void* g, void* l) {
    __builtin_amdgcn_global_load_lds((const __attribute__((address_space(1))) unsigned int*)g,
                                     (__attribute__((address_space(3))) unsigned int*)l, 16, 0, 0);
}

// ---------------- fused prep: x convert + 5 weight transposes (one dispatch) ----------------
// region layout (blockIdx.x):
//   [0,1024)     x fp32 -> bf16 straight copy (4096 el/block)
//   [1024,2048)  Wq  [2048][2048] -> WcatT rows 0..2047     (64x64 tiles)
//   [2048,2304)  Wk  [2048][512]  -> WcatT rows 2048..2559
//   [2304,2560)  Wv  [2048][512]  -> WcatT rows 2560..3071
//   [2560,3584)  Wg  [2048][2048] -> WcatT rows 3072..5119
//   [3584,4608)  Wo  [2048][2048] -> WoT
__global__ __launch_bounds__(256) void k_prep(
        const float* __restrict__ x,
        const float* __restrict__ Wq, const float* __restrict__ Wk,
        const float* __restrict__ Wv, const float* __restrict__ Wg,
        const float* __restrict__ Wo,
        unsigned short* __restrict__ xb,
        unsigned short* __restrict__ WcatT,
        unsigned short* __restrict__ WoT) {
    const int bid = blockIdx.x;
    const int t = threadIdx.x;
    if (bid < 1024) {                       // x convert
        size_t base = (size_t)bid * 4096 + t * 16;
#pragma unroll
        for (int i = 0; i < 4; i++) {
            float4 v = *(const float4*)&x[base + i * 4];
            ushort4 o;
            o.x = f2bf(v.x); o.y = f2bf(v.y); o.z = f2bf(v.z); o.w = f2bf(v.w);
            *(ushort4*)&xb[base + i * 4] = o;
        }
        return;
    }
    const float* src; unsigned short* dst; int N, rowOff, tile;
    if (bid < 2048)      { src = Wq; dst = WcatT; N = 2048; rowOff = 0;    tile = bid - 1024; }
    else if (bid < 2304) { src = Wk; dst = WcatT; N = 512;  rowOff = 2048; tile = bid - 2048; }
    else if (bid < 2560) { src = Wv; dst = WcatT; N = 512;  rowOff = 2560; tile = bid - 2304; }
    else if (bid < 3584) { src = Wg; dst = WcatT; N = 2048; rowOff = 3072; tile = bid - 2560; }
    else                 { src = Wo; dst = WoT;   N = 2048; rowOff = 0;    tile = bid - 3584; }
    const int ntx = N >> 6;
    const int n0 = (tile % ntx) * 64;
    const int k0 = (tile / ntx) * 64;
    __shared__ float tl[64][65];            // +1 pad: column read = bank walk, 2-way only
    const int r = t >> 2, q = t & 3;
    // read: per i, lanes (q=0..3) cover 64B contiguous of row r
#pragma unroll
    for (int i = 0; i < 4; i++) {
        const int c = q * 4 + i * 16;
        float4 v = *(const float4*)&src[(size_t)(k0 + r) * N + n0 + c];
        tl[r][c] = v.x; tl[r][c + 1] = v.y; tl[r][c + 2] = v.z; tl[r][c + 3] = v.w;
    }
    __syncthreads();
    // write: output row n = n0+r, this thread covers k = k0+q*16 .. +15 (32B, 16B stores)
    unsigned short obuf[16] __attribute__((aligned(16)));
#pragma unroll
    for (int i = 0; i < 16; i++) obuf[i] = f2bf(tl[q * 16 + i][r]);
    const size_t off = (size_t)(rowOff + n0 + r) * 2048 + k0 + q * 16;
    *(uint4*)&dst[off] = ((uint4*)obuf)[0];
    *(uint4*)&dst[off + 8] = ((uint4*)obuf)[1];
}

// ---------------- output GEMM: 128x64 tile (2048^3 is occupancy-starved at 128^2) ----------------
// 512 blocks = 2/CU (vs 1/CU at 128^2). 4 waves: 2x2 of 64x32. LDS 24KB.
__global__ __launch_bounds__(256) void k_gemm_out(
        const unsigned short* __restrict__ A,
        const unsigned short* __restrict__ Bt,
        float* __restrict__ C) {
    const int K = 2048, NN = 2048;
    __shared__ __align__(16) unsigned short As[128 * 64];
    __shared__ __align__(16) unsigned short Bs[64 * 64];
    const int tid = threadIdx.x;
    const int lane = tid & 63;
    const int w = tid >> 6;
    const int wm = (w >> 1) * 64, wn = (w & 1) * 32;
    const int bm0 = blockIdx.y * 128, bn0 = blockIdx.x * 64;
    const int lr = lane & 15;
    const int lk = (lane >> 4) * 8;
    const int srow_in = lane >> 3;
    const int scol = (lane & 7) * 8;

    f32x4 acc[4][2] = {};

    for (int k0 = 0; k0 < K; k0 += 64) {
        __syncthreads();
#pragma unroll
        for (int p = 0; p < 4; p++) {
            int chunk = p * 4 + w;
            int row = chunk * 8 + srow_in;
            gload16(&A[(size_t)(bm0 + row) * K + k0 + scol], &As[chunk * 512]);
        }
#pragma unroll
        for (int c = 0; c < 2; c++) {
            int chunk = w * 2 + c;
            int row = chunk * 8 + srow_in;
            gload16(&Bt[(size_t)(bn0 + row) * K + k0 + scol], &Bs[chunk * 512]);
        }
        __syncthreads();
#pragma unroll
        for (int kc = 0; kc < 2; kc++) {
            bfrag af[4], bfr[2];
#pragma unroll
            for (int tt = 0; tt < 4; tt++)
                af[tt] = *(const bfrag*)&As[(wm + tt * 16 + lr) * 64 + kc * 32 + lk];
#pragma unroll
            for (int tt = 0; tt < 2; tt++)
                bfr[tt] = *(const bfrag*)&Bs[(wn + tt * 16 + lr) * 64 + kc * 32 + lk];
#pragma unroll
            for (int mt = 0; mt < 4; mt++)
#pragma unroll
                for (int nt = 0; nt < 2; nt++)
                    acc[mt][nt] = __builtin_amdgcn_mfma_f32_16x16x32_bf16(af[mt], bfr[nt], acc[mt][nt], 0, 0, 0);
        }
    }
    const int orow = (lane >> 4) * 4;
#pragma unroll
    for (int mt = 0; mt < 4; mt++)
#pragma unroll
        for (int nt = 0; nt < 2; nt++)
#pragma unroll
            for (int j = 0; j < 4; j++)
                C[(size_t)(bm0 + wm + mt * 16 + orow + j) * NN + bn0 + wn + nt * 16 + lr] = acc[mt][nt][j];
}

// ---------------- projection GEMM with FUSED epilogue (RoPE / v-transpose / sigmoid gate) ----------------
// bcol 0..15 = q (RoPE, pre-scaled bf16) | 16..19 = k (RoPE, bf16 + fp32 out)
//   | 20..23 = v (transposed bf16 + fp32 out) | 24..39 = gate (sigmoid bf16)
// RoPE partner (d +/- 32) lives in the SAME thread's acc at nt^2.
// __launch_bounds__(256,4): R7->R8 measured: caps VGPR (140->64), restores occupancy
// (9.2->21%), MfmaUtil 10.5->19.5, dur 162.7->88.2 us. Do not remove.
__global__ __launch_bounds__(256, 4) void k_gemm_proj(
        const unsigned short* __restrict__ A,
        const unsigned short* __restrict__ Bt,
        const float* __restrict__ rc, const float* __restrict__ rs,
        const float* __restrict__ bg,
        unsigned short* __restrict__ qb,    // [HQ][S][64]
        unsigned short* __restrict__ kbuf,  // [HKV][S][64]
        unsigned short* __restrict__ vt,    // [HKV][64][S]
        unsigned short* __restrict__ alpha, // [S][2048]
        float* __restrict__ outk, float* __restrict__ outv) {
    __shared__ __align__(16) unsigned short As[128 * 64];
    __shared__ __align__(16) unsigned short Bs[128 * 64];
    const int tid = threadIdx.x;
    const int lane = tid & 63;
    const int w = tid >> 6;
    const int wm = (w >> 1) * 64, wn = (w & 1) * 64;
    const int bcol = blockIdx.x;
    const int bm0 = blockIdx.y * 128, bn0 = bcol * 128;
    const int lr = lane & 15;
    const int lk = (lane >> 4) * 8;
    const int srow_in = lane >> 3;
    const int scol = (lane & 7) * 8;
    const int K = HID_DIM;

    f32x4 acc[4][4] = {};

    for (int k0 = 0; k0 < K; k0 += 64) {
        __syncthreads();
#pragma unroll
        for (int p = 0; p < 4; p++) {
            int chunk = p * 4 + w;
            int row = chunk * 8 + srow_in;
            gload16(&A[(size_t)(bm0 + row) * K + k0 + scol], &As[chunk * 512]);
            gload16(&Bt[(size_t)(bn0 + row) * K + k0 + scol], &Bs[chunk * 512]);
        }
        __syncthreads();
#pragma unroll
        for (int kc = 0; kc < 2; kc++) {
            bfrag af[4], bfr[4];
#pragma unroll
            for (int t = 0; t < 4; t++)
                af[t] = *(const bfrag*)&As[(wm + t * 16 + lr) * 64 + kc * 32 + lk];
#pragma unroll
            for (int t = 0; t < 4; t++)
                bfr[t] = *(const bfrag*)&Bs[(wn + t * 16 + lr) * 64 + kc * 32 + lk];
#pragma unroll
            for (int mt = 0; mt < 4; mt++)
#pragma unroll
                for (int nt = 0; nt < 4; nt++)
                    acc[mt][nt] = __builtin_amdgcn_mfma_f32_16x16x32_bf16(af[mt], bfr[nt], acc[mt][nt], 0, 0, 0);
        }
    }

    const int orow = (lane >> 4) * 4;
    if (bcol < 20) {
        // q or k: RoPE in-register. d = (wn+nt*16+lr)&63; d<32 <=> nt<2; partner at nt^2.
        const bool isq = (bcol < 16);
#pragma unroll
        for (int mt = 0; mt < 4; mt++)
#pragma unroll
            for (int j = 0; j < 4; j++) {
                const int s = bm0 + wm + mt * 16 + orow + j;
#pragma unroll
                for (int nt = 0; nt < 4; nt++) {
                    const int n = bn0 + wn + nt * 16 + lr;
                    const int d = n & 63;
                    const float c = rc[(s << 6) + d];
                    const float sn = rs[(s << 6) + d];
                    const float val = acc[mt][nt][j];
                    const float partner = acc[mt][nt ^ 2][j];
                    const float rot = (nt < 2) ? -partner : partner;
                    const float o = val * c + rot * sn;
                    if (isq) {
                        const int h = n >> 6;
                        qb[((size_t)h * S_LEN + s) * 64 + d] = f2bf(o * QSCALE_LOG2);
                    } else {
                        const int h = (n - 2048) >> 6;
                        const size_t oidx = ((size_t)h * S_LEN + s) * 64 + d;
                        kbuf[oidx] = f2bf(o);
                        outk[oidx] = o;
                    }
                }
            }
    } else if (bcol < 24) {
        // v: transposed bf16 + fp32 out
#pragma unroll
        for (int mt = 0; mt < 4; mt++)
#pragma unroll
            for (int j = 0; j < 4; j++) {
                const int s = bm0 + wm + mt * 16 + orow + j;
#pragma unroll
                for (int nt = 0; nt < 4; nt++) {
                    const int n = bn0 + wn + nt * 16 + lr;
                    const int h = (n - 2560) >> 6;
                    const int d = n & 63;
                    const float val = acc[mt][nt][j];
                    vt[((size_t)h * 64 + d) * S_LEN + s] = f2bf(val);
                    outv[((size_t)h * S_LEN + s) * 64 + d] = val;
                }
            }
    } else {
        // gate: sigmoid(val + bg)
#pragma unroll
        for (int mt = 0; mt < 4; mt++)
#pragma unroll
            for (int j = 0; j < 4; j++) {
                const int s = bm0 + wm + mt * 16 + orow + j;
#pragma unroll
                for (int nt = 0; nt < 4; nt++) {
                    const int n = bn0 + wn + nt * 16 + lr;
                    const int m = n - 3072;
                    const float a = 1.0f / (1.0f + __expf(-(acc[mt][nt][j] + bg[m])));
                    alpha[(size_t)s * 2048 + m] = f2bf(a);
                }
            }
    }
}

// ---------------- flash attention (causal, GQA) + FUSED GroupNorm*gate ----------------
// 2-phase pipelined: double-buffered K/V LDS via async global_load_lds (linear dest,
// pre-swizzled global source; same XOR on ds_read side -> 2-way banks = free).
// Block = 64 q-rows x 1 head, 4 waves x 16 rows. One barrier per KV tile.
__global__ __launch_bounds__(256) void k_attn(
        const unsigned short* __restrict__ qb,
        const unsigned short* __restrict__ kbuf,
        const unsigned short* __restrict__ vt,
        const unsigned short* __restrict__ alpha,
        const float* __restrict__ gnw, const float* __restrict__ gnb,
        unsigned short* __restrict__ gno) {  // [S][2048]
    __shared__ __align__(16) unsigned short Ks[2][64 * 64];
    __shared__ __align__(16) unsigned short Vs[2][64 * 64];
    __shared__ __align__(16) unsigned short Ps[4][16 * 72];
    const int tid = threadIdx.x;
    const int lane = tid & 63;
    const int w = tid >> 6;
    const int lr = lane & 15;
    const int lg = lane >> 4;
    const int lk = lg * 8;

    const int bid = blockIdx.x;
    const int qblk = 31 - (bid >> 5);        // heavy blocks dispatched first
    const int h = bid & 31;
    const int hk = h >> 2;
    const int r0 = qblk * 64 + w * 16;

    // swizzled LDS read offsets (ushort units)
    const int swzkey = (lr & 7) << 4;
    const int swz0 = ((lg * 16) ^ swzkey) >> 1;
    const int swz1 = ((64 + lg * 16) ^ swzkey) >> 1;
    // staging: pre-swizzled global source col so linear LDS + swizzled read = identity
    const int srow = lane >> 3;
    const int scol = (((lane & 7) ^ srow) << 3);

    const unsigned short* Kg = &kbuf[(size_t)hk * S_LEN * 64];
    const unsigned short* Vg = &vt[(size_t)hk * 64 * S_LEN];

    bfrag qf[2];
    {
        const unsigned short* qrow = &qb[((size_t)h * S_LEN + r0 + lr) * 64];
        qf[0] = *(const bfrag*)&qrow[lk];
        qf[1] = *(const bfrag*)&qrow[32 + lk];
    }

    float m_r[4], l_r[4];
    f32x4 o_acc[4] = {};
#pragma unroll
    for (int j = 0; j < 4; j++) { m_r[j] = -1e30f; l_r[j] = 0.0f; }

#define STAGE(buf, kb)                                                                  \
    {                                                                                   \
        _Pragma("unroll")                                                               \
        for (int c = 0; c < 2; c++) {                                                   \
            int chunk = w * 2 + c;                                                      \
            gload16(&Kg[(size_t)((kb) * 64 + chunk * 8 + srow) * 64 + scol],            \
                    &Ks[buf][chunk * 512]);                                             \
            gload16(&Vg[(size_t)(chunk * 8 + srow) * S_LEN + (kb) * 64 + scol],         \
                    &Vs[buf][chunk * 512]);                                             \
        }                                                                               \
    }

    const int nt = qblk + 1;
    STAGE(0, 0);
    __syncthreads();
    int cur = 0;

    for (int kb = 0; kb < nt; kb++) {
        if (kb + 1 < nt) STAGE(cur ^ 1, kb + 1);
        const unsigned short* Kc = Ks[cur];
        const unsigned short* Vc = Vs[cur];
        // ---- QK^T ----
        f32x4 sacc[4] = {};
        __builtin_amdgcn_s_setprio(1);
#pragma unroll
        for (int g = 0; g < 4; g++) {
            bfrag kf0 = *(const bfrag*)&Kc[g * 1024 + lr * 64 + swz0];
            bfrag kf1 = *(const bfrag*)&Kc[g * 1024 + lr * 64 + swz1];
            sacc[g] = __builtin_amdgcn_mfma_f32_16x16x32_bf16(qf[0], kf0, sacc[g], 0, 0, 0);
            sacc[g] = __builtin_amdgcn_mfma_f32_16x16x32_bf16(qf[1], kf1, sacc[g], 0, 0, 0);
        }
        __builtin_amdgcn_s_setprio(0);
        if (kb == qblk) {
#pragma unroll
            for (int g = 0; g < 4; g++)
#pragma unroll
                for (int j = 0; j < 4; j++) {
                    int col = kb * 64 + g * 16 + lr;
                    int row = r0 + lg * 4 + j;
                    if (col > row) sacc[g][j] = -1e30f;
                }
        }
        // ---- online softmax (base-2) ----
        float ps[4];
#pragma unroll
        for (int j = 0; j < 4; j++) {
            float tv = fmaxf(fmaxf(sacc[0][j], sacc[1][j]), fmaxf(sacc[2][j], sacc[3][j]));
#pragma unroll
            for (int msk = 1; msk < 16; msk <<= 1)
                tv = fmaxf(tv, __shfl_xor(tv, msk, 64));
            float mnew = fmaxf(m_r[j], tv);
            float sc = exp2f(m_r[j] - mnew);
            m_r[j] = mnew;
            l_r[j] *= sc;
#pragma unroll
            for (int g = 0; g < 4; g++) o_acc[g][j] *= sc;
            ps[j] = 0.0f;
        }
#pragma unroll
        for (int g = 0; g < 4; g++)
#pragma unroll
            for (int j = 0; j < 4; j++) {
                float p = exp2f(sacc[g][j] - m_r[j]);
                ps[j] += p;
                Ps[w][(lg * 4 + j) * 72 + g * 16 + lr] = f2bf(p);
            }
#pragma unroll
        for (int j = 0; j < 4; j++) {
            float pv = ps[j];
#pragma unroll
            for (int msk = 1; msk < 16; msk <<= 1)
                pv += __shfl_xor(pv, msk, 64);
            l_r[j] += pv;
        }
        bfrag pf0 = *(const bfrag*)&Ps[w][lr * 72 + lk];
        bfrag pf1 = *(const bfrag*)&Ps[w][lr * 72 + 32 + lk];
        // ---- PV ----
        __builtin_amdgcn_s_setprio(1);
#pragma unroll
        for (int g = 0; g < 4; g++) {
            bfrag vf0 = *(const bfrag*)&Vc[g * 1024 + lr * 64 + swz0];
            bfrag vf1 = *(const bfrag*)&Vc[g * 1024 + lr * 64 + swz1];
            o_acc[g] = __builtin_amdgcn_mfma_f32_16x16x32_bf16(pf0, vf0, o_acc[g], 0, 0, 0);
            o_acc[g] = __builtin_amdgcn_mfma_f32_16x16x32_bf16(pf1, vf1, o_acc[g], 0, 0, 0);
        }
        __builtin_amdgcn_s_setprio(0);
        __syncthreads();
        cur ^= 1;
    }
#undef STAGE

    // ---- fused GroupNorm(D=64) * gate ----
    float gv[4][4];
#pragma unroll
    for (int j = 0; j < 4; j++) {
        const float inv = 1.0f / (l_r[j] + 1e-9f);
#pragma unroll
        for (int g = 0; g < 4; g++) gv[g][j] = o_acc[g][j] * inv;
    }
#pragma unroll
    for (int j = 0; j < 4; j++) {
        float sum = gv[0][j] + gv[1][j] + gv[2][j] + gv[3][j];
#pragma unroll
        for (int msk = 1; msk < 16; msk <<= 1) sum += __shfl_xor(sum, msk, 64);
        const float mu = sum * (1.0f / 64.0f);
        float vs = 0.0f;
#pragma unroll
        for (int g = 0; g < 4; g++) { float dd = gv[g][j] - mu; vs += dd * dd; }
#pragma unroll
        for (int msk = 1; msk < 16; msk <<= 1) vs += __shfl_xor(vs, msk, 64);
        const float rstd = rsqrtf(vs * (1.0f / 64.0f) + 1e-5f);
        const int s = r0 + lg * 4 + j;
#pragma unroll
        for (int g = 0; g < 4; g++) {
            const int col = (h << 6) + g * 16 + lr;
            const float gn = (gv[g][j] - mu) * rstd * gnw[col] + gnb[col];
            const float a = bf2f(alpha[(size_t)s * 2048 + col]);
            gno[(size_t)s * 2048 + col] = f2bf(gn * a);
        }
    }
}

extern "C" void kernel_launch(void* const* d_in, const int* in_sizes, int n_in,
                              void* d_out, int out_size, void* d_ws, size_t ws_size,
                              hipStream_t stream) {
    const float* x   = (const float*)d_in[0];
    const float* rc  = (const float*)d_in[1];
    const float* rs  = (const float*)d_in[2];
    const float* Wq  = (const float*)d_in[3];
    const float* Wk  = (const float*)d_in[4];
    const float* Wv  = (const float*)d_in[5];
    const float* Wo  = (const float*)d_in[6];
    const float* Wg  = (const float*)d_in[7];
    const float* bg  = (const float*)d_in[8];
    const float* gnw = (const float*)d_in[9];
    const float* gnb = (const float*)d_in[10];
    float* out = (float*)d_out;

    char* ws = (char*)d_ws;
    unsigned short* xb    = (unsigned short*)(ws);                      // 8 MB
    unsigned short* WcatT = (unsigned short*)(ws + 8388608);            // 20 MB
    unsigned short* WoT   = (unsigned short*)(ws + 29360128);           // 8 MB
    unsigned short* alpha = (unsigned short*)(ws + 37748736);           // 8 MB
    unsigned short* qb    = (unsigned short*)(ws + 46137344);           // 8 MB
    unsigned short* kbuf  = (unsigned short*)(ws + 54525952);           // 2 MB
    unsigned short* vt    = (unsigned short*)(ws + 56623104);           // 2 MB
    unsigned short* gno   = (unsigned short*)(ws + 58720256);           // 8 MB

    hipLaunchKernelGGL(k_prep, dim3(4608), dim3(256), 0, stream,
                       x, Wq, Wk, Wv, Wg, Wo, xb, WcatT, WoT);

    float* outk = out + (size_t)4 * 1024 * 1024;
    float* outv = out + (size_t)5 * 1024 * 1024;

    hipLaunchKernelGGL(k_gemm_proj, dim3(5120 / 128, 2048 / 128), dim3(256), 0, stream,
                       xb, WcatT, rc, rs, bg, qb, kbuf, vt, alpha, outk, outv);

    hipLaunchKernelGGL(k_attn, dim3(1024), dim3(256), 0, stream,
                       qb, kbuf, vt, alpha, gnw, gnb, gno);

    hipLaunchKernelGGL(k_gemm_out, dim3(2048 / 64, 2048 / 128), dim3(256), 0, stream,
                       gno, WoT, out);
}

// Round 15
// 305.499 us; speedup vs baseline: 1.3278x; 1.0114x over previous
//
#include <hip/hip_runtime.h>
#include <hip/hip_bf16.h>
#include <stdint.h>

#define S_LEN 2048
#define HID_DIM 2048
#define HQ 32
#define HKV 8
#define NPROJ 5120   // 2048 q | 512 k | 512 v | 2048 g
// Q pre-scale: attention scale * log2(e), so softmax runs in base-2 (v_exp_f32 native)
#define QSCALE_LOG2 (0.125f * 1.44269504088896f)

using f32x4 = __attribute__((ext_vector_type(4))) float;
using bfrag = __attribute__((ext_vector_type(8))) short;

__device__ __forceinline__ unsigned short f2bf(float f) {
    union { float f; unsigned u; } a; a.f = f;
    unsigned r = a.u + 0x7fffu + ((a.u >> 16) & 1u);
    return (unsigned short)(r >> 16);
}
__device__ __forceinline__ float bf2f(unsigned short h) {
    union { unsigned u; float f; } a; a.u = ((unsigned)h) << 16;
    return a.f;
}

// async global->LDS, 16B per lane; LDS dest must be wave-uniform base (+lane*16 implicit)
__device__ __forceinline__ void gload16(const void* g, void* l) {
    __builtin_amdgcn_global_load_lds((const __attribute__((address_space(1))) unsigned int*)g,
                                     (__attribute__((address_space(3))) unsigned int*)l, 16, 0, 0);
}

// ---------------- fused prep: x convert + 5 weight transposes (one dispatch) ----------------
__global__ __launch_bounds__(256) void k_prep(
        const float* __restrict__ x,
        const float* __restrict__ Wq, const float* __restrict__ Wk,
        const float* __restrict__ Wv, const float* __restrict__ Wg,
        const float* __restrict__ Wo,
        unsigned short* __restrict__ xb,
        unsigned short* __restrict__ WcatT,
        unsigned short* __restrict__ WoT) {
    const int bid = blockIdx.x;
    const int t = threadIdx.x;
    if (bid < 1024) {                       // x convert
        size_t base = (size_t)bid * 4096 + t * 16;
#pragma unroll
        for (int i = 0; i < 4; i++) {
            float4 v = *(const float4*)&x[base + i * 4];
            ushort4 o;
            o.x = f2bf(v.x); o.y = f2bf(v.y); o.z = f2bf(v.z); o.w = f2bf(v.w);
            *(ushort4*)&xb[base + i * 4] = o;
        }
        return;
    }
    const float* src; unsigned short* dst; int N, rowOff, tile;
    if (bid < 2048)      { src = Wq; dst = WcatT; N = 2048; rowOff = 0;    tile = bid - 1024; }
    else if (bid < 2304) { src = Wk; dst = WcatT; N = 512;  rowOff = 2048; tile = bid - 2048; }
    else if (bid < 2560) { src = Wv; dst = WcatT; N = 512;  rowOff = 2560; tile = bid - 2304; }
    else if (bid < 3584) { src = Wg; dst = WcatT; N = 2048; rowOff = 3072; tile = bid - 2560; }
    else                 { src = Wo; dst = WoT;   N = 2048; rowOff = 0;    tile = bid - 3584; }
    const int ntx = N >> 6;
    const int n0 = (tile % ntx) * 64;
    const int k0 = (tile / ntx) * 64;
    __shared__ float tl[64][65];            // +1 pad: column read = bank walk, 2-way only
    const int r = t >> 2, q = t & 3;
#pragma unroll
    for (int i = 0; i < 4; i++) {
        const int c = q * 4 + i * 16;
        float4 v = *(const float4*)&src[(size_t)(k0 + r) * N + n0 + c];
        tl[r][c] = v.x; tl[r][c + 1] = v.y; tl[r][c + 2] = v.z; tl[r][c + 3] = v.w;
    }
    __syncthreads();
    unsigned short obuf[16] __attribute__((aligned(16)));
#pragma unroll
    for (int i = 0; i < 16; i++) obuf[i] = f2bf(tl[q * 16 + i][r]);
    const size_t off = (size_t)(rowOff + n0 + r) * 2048 + k0 + q * 16;
    *(uint4*)&dst[off] = ((uint4*)obuf)[0];
    *(uint4*)&dst[off + 8] = ((uint4*)obuf)[1];
}

// ---------------- output GEMM: 128x64 tile (2048^3 is occupancy-starved at 128^2) ----------------
__global__ __launch_bounds__(256) void k_gemm_out(
        const unsigned short* __restrict__ A,
        const unsigned short* __restrict__ Bt,
        float* __restrict__ C) {
    const int K = 2048, NN = 2048;
    __shared__ __align__(16) unsigned short As[128 * 64];
    __shared__ __align__(16) unsigned short Bs[64 * 64];
    const int tid = threadIdx.x;
    const int lane = tid & 63;
    const int w = tid >> 6;
    const int wm = (w >> 1) * 64, wn = (w & 1) * 32;
    const int bm0 = blockIdx.y * 128, bn0 = blockIdx.x * 64;
    const int lr = lane & 15;
    const int lk = (lane >> 4) * 8;
    const int srow_in = lane >> 3;
    const int scol = (lane & 7) * 8;

    f32x4 acc[4][2] = {};

    for (int k0 = 0; k0 < K; k0 += 64) {
        __syncthreads();
#pragma unroll
        for (int p = 0; p < 4; p++) {
            int chunk = p * 4 + w;
            int row = chunk * 8 + srow_in;
            gload16(&A[(size_t)(bm0 + row) * K + k0 + scol], &As[chunk * 512]);
        }
#pragma unroll
        for (int c = 0; c < 2; c++) {
            int chunk = w * 2 + c;
            int row = chunk * 8 + srow_in;
            gload16(&Bt[(size_t)(bn0 + row) * K + k0 + scol], &Bs[chunk * 512]);
        }
        __syncthreads();
#pragma unroll
        for (int kc = 0; kc < 2; kc++) {
            bfrag af[4], bfr[2];
#pragma unroll
            for (int tt = 0; tt < 4; tt++)
                af[tt] = *(const bfrag*)&As[(wm + tt * 16 + lr) * 64 + kc * 32 + lk];
#pragma unroll
            for (int tt = 0; tt < 2; tt++)
                bfr[tt] = *(const bfrag*)&Bs[(wn + tt * 16 + lr) * 64 + kc * 32 + lk];
#pragma unroll
            for (int mt = 0; mt < 4; mt++)
#pragma unroll
                for (int nt = 0; nt < 2; nt++)
                    acc[mt][nt] = __builtin_amdgcn_mfma_f32_16x16x32_bf16(af[mt], bfr[nt], acc[mt][nt], 0, 0, 0);
        }
    }
    const int orow = (lane >> 4) * 4;
#pragma unroll
    for (int mt = 0; mt < 4; mt++)
#pragma unroll
        for (int nt = 0; nt < 2; nt++)
#pragma unroll
            for (int j = 0; j < 4; j++)
                C[(size_t)(bm0 + wm + mt * 16 + orow + j) * NN + bn0 + wn + nt * 16 + lr] = acc[mt][nt][j];
}

// ---------------- projection GEMM, 128x64 tile, FUSED epilogue ----------------
// R11: proj was grid-limited (640 blocks = 2.5/CU, Occupancy 23%). 128x64 tiling ->
// 80x16 = 1280 blocks = 5/CU. Wave = 32 rows x 64 cols so each head's D=64 stays in
// one thread's acc; RoPE partner (d +/- 32) = acc[mt][nt^2] as before.
// Regions per bcol (64-col granularity): [0,32) q | [32,40) k | [40,48) v | [48,80) gate.
// __launch_bounds__(256,4): R7->R8 occupancy-cliff fix. Do not remove.
__global__ __launch_bounds__(256, 4) void k_gemm_proj(
        const unsigned short* __restrict__ A,
        const unsigned short* __restrict__ Bt,
        const float* __restrict__ rc, const float* __restrict__ rs,
        const float* __restrict__ bg,
        unsigned short* __restrict__ qb,    // [HQ][S][64]
        unsigned short* __restrict__ kbuf,  // [HKV][S][64]
        unsigned short* __restrict__ vt,    // [HKV][64][S]
        unsigned short* __restrict__ alpha, // [S][2048]
        float* __restrict__ outk, float* __restrict__ outv) {
    __shared__ __align__(16) unsigned short As[128 * 64];
    __shared__ __align__(16) unsigned short Bs[64 * 64];
    const int tid = threadIdx.x;
    const int lane = tid & 63;
    const int w = tid >> 6;
    const int wm = w * 32;                  // wave = 32 rows x full 64 cols
    const int bcol = blockIdx.x;
    const int bm0 = blockIdx.y * 128, bn0 = bcol * 64;
    const int lr = lane & 15;
    const int lk = (lane >> 4) * 8;
    const int srow_in = lane >> 3;
    const int scol = (lane & 7) * 8;
    const int K = HID_DIM;

    f32x4 acc[2][4] = {};

    for (int k0 = 0; k0 < K; k0 += 64) {
        __syncthreads();
#pragma unroll
        for (int p = 0; p < 4; p++) {
            int chunk = p * 4 + w;
            int row = chunk * 8 + srow_in;
            gload16(&A[(size_t)(bm0 + row) * K + k0 + scol], &As[chunk * 512]);
        }
#pragma unroll
        for (int c = 0; c < 2; c++) {
            int chunk = w * 2 + c;
            int row = chunk * 8 + srow_in;
            gload16(&Bt[(size_t)(bn0 + row) * K + k0 + scol], &Bs[chunk * 512]);
        }
        __syncthreads();
#pragma unroll
        for (int kc = 0; kc < 2; kc++) {
            bfrag af[2], bfr[4];
#pragma unroll
            for (int t = 0; t < 2; t++)
                af[t] = *(const bfrag*)&As[(wm + t * 16 + lr) * 64 + kc * 32 + lk];
#pragma unroll
            for (int t = 0; t < 4; t++)
                bfr[t] = *(const bfrag*)&Bs[(t * 16 + lr) * 64 + kc * 32 + lk];
#pragma unroll
            for (int mt = 0; mt < 2; mt++)
#pragma unroll
                for (int nt = 0; nt < 4; nt++)
                    acc[mt][nt] = __builtin_amdgcn_mfma_f32_16x16x32_bf16(af[mt], bfr[nt], acc[mt][nt], 0, 0, 0);
        }
    }

    const int orow = (lane >> 4) * 4;
    if (bcol < 40) {
        // q or k: RoPE in-register. d = nt*16+lr; d<32 <=> nt<2; partner at nt^2.
        const bool isq = (bcol < 32);
#pragma unroll
        for (int mt = 0; mt < 2; mt++)
#pragma unroll
            for (int j = 0; j < 4; j++) {
                const int s = bm0 + wm + mt * 16 + orow + j;
#pragma unroll
                for (int nt = 0; nt < 4; nt++) {
                    const int d = nt * 16 + lr;
                    const float c = rc[(s << 6) + d];
                    const float sn = rs[(s << 6) + d];
                    const float val = acc[mt][nt][j];
                    const float partner = acc[mt][nt ^ 2][j];
                    const float rot = (nt < 2) ? -partner : partner;
                    const float o = val * c + rot * sn;
                    if (isq) {
                        const int h = bcol;
                        qb[((size_t)h * S_LEN + s) * 64 + d] = f2bf(o * QSCALE_LOG2);
                    } else {
                        const int h = bcol - 32;
                        const size_t oidx = ((size_t)h * S_LEN + s) * 64 + d;
                        kbuf[oidx] = f2bf(o);
                        outk[oidx] = o;
                    }
                }
            }
    } else if (bcol < 48) {
        // v: transposed bf16 + fp32 out
        const int h = bcol - 40;
#pragma unroll
        for (int mt = 0; mt < 2; mt++)
#pragma unroll
            for (int j = 0; j < 4; j++) {
                const int s = bm0 + wm + mt * 16 + orow + j;
#pragma unroll
                for (int nt = 0; nt < 4; nt++) {
                    const int d = nt * 16 + lr;
                    const float val = acc[mt][nt][j];
                    vt[((size_t)h * 64 + d) * S_LEN + s] = f2bf(val);
                    outv[((size_t)h * S_LEN + s) * 64 + d] = val;
                }
            }
    } else {
        // gate: sigmoid(val + bg)
        const int m0 = (bcol - 48) * 64;
#pragma unroll
        for (int mt = 0; mt < 2; mt++)
#pragma unroll
            for (int j = 0; j < 4; j++) {
                const int s = bm0 + wm + mt * 16 + orow + j;
#pragma unroll
                for (int nt = 0; nt < 4; nt++) {
                    const int m = m0 + nt * 16 + lr;
                    const float a = 1.0f / (1.0f + __expf(-(acc[mt][nt][j] + bg[m])));
                    alpha[(size_t)s * 2048 + m] = f2bf(a);
                }
            }
    }
}

// ---------------- flash attention (causal, GQA) + FUSED GroupNorm*gate ----------------
__global__ __launch_bounds__(256) void k_attn(
        const unsigned short* __restrict__ qb,
        const unsigned short* __restrict__ kbuf,
        const unsigned short* __restrict__ vt,
        const unsigned short* __restrict__ alpha,
        const float* __restrict__ gnw, const float* __restrict__ gnb,
        unsigned short* __restrict__ gno) {  // [S][2048]
    __shared__ __align__(16) unsigned short Ks[2][64 * 64];
    __shared__ __align__(16) unsigned short Vs[2][64 * 64];
    __shared__ __align__(16) unsigned short Ps[4][16 * 72];
    const int tid = threadIdx.x;
    const int lane = tid & 63;
    const int w = tid >> 6;
    const int lr = lane & 15;
    const int lg = lane >> 4;
    const int lk = lg * 8;

    const int bid = blockIdx.x;
    const int qblk = 31 - (bid >> 5);        // heavy blocks dispatched first
    const int h = bid & 31;
    const int hk = h >> 2;
    const int r0 = qblk * 64 + w * 16;

    const int swzkey = (lr & 7) << 4;
    const int swz0 = ((lg * 16) ^ swzkey) >> 1;
    const int swz1 = ((64 + lg * 16) ^ swzkey) >> 1;
    const int srow = lane >> 3;
    const int scol = (((lane & 7) ^ srow) << 3);

    const unsigned short* Kg = &kbuf[(size_t)hk * S_LEN * 64];
    const unsigned short* Vg = &vt[(size_t)hk * 64 * S_LEN];

    bfrag qf[2];
    {
        const unsigned short* qrow = &qb[((size_t)h * S_LEN + r0 + lr) * 64];
        qf[0] = *(const bfrag*)&qrow[lk];
        qf[1] = *(const bfrag*)&qrow[32 + lk];
    }

    float m_r[4], l_r[4];
    f32x4 o_acc[4] = {};
#pragma unroll
    for (int j = 0; j < 4; j++) { m_r[j] = -1e30f; l_r[j] = 0.0f; }

#define STAGE(buf, kb)                                                                  \
    {                                                                                   \
        _Pragma("unroll")                                                               \
        for (int c = 0; c < 2; c++) {                                                   \
            int chunk = w * 2 + c;                                                      \
            gload16(&Kg[(size_t)((kb) * 64 + chunk * 8 + srow) * 64 + scol],            \
                    &Ks[buf][chunk * 512]);                                             \
            gload16(&Vg[(size_t)(chunk * 8 + srow) * S_LEN + (kb) * 64 + scol],         \
                    &Vs[buf][chunk * 512]);                                             \
        }                                                                               \
    }

    const int nt = qblk + 1;
    STAGE(0, 0);
    __syncthreads();
    int cur = 0;

    for (int kb = 0; kb < nt; kb++) {
        if (kb + 1 < nt) STAGE(cur ^ 1, kb + 1);
        const unsigned short* Kc = Ks[cur];
        const unsigned short* Vc = Vs[cur];
        // ---- QK^T ----
        f32x4 sacc[4] = {};
        __builtin_amdgcn_s_setprio(1);
#pragma unroll
        for (int g = 0; g < 4; g++) {
            bfrag kf0 = *(const bfrag*)&Kc[g * 1024 + lr * 64 + swz0];
            bfrag kf1 = *(const bfrag*)&Kc[g * 1024 + lr * 64 + swz1];
            sacc[g] = __builtin_amdgcn_mfma_f32_16x16x32_bf16(qf[0], kf0, sacc[g], 0, 0, 0);
            sacc[g] = __builtin_amdgcn_mfma_f32_16x16x32_bf16(qf[1], kf1, sacc[g], 0, 0, 0);
        }
        __builtin_amdgcn_s_setprio(0);
        if (kb == qblk) {
#pragma unroll
            for (int g = 0; g < 4; g++)
#pragma unroll
                for (int j = 0; j < 4; j++) {
                    int col = kb * 64 + g * 16 + lr;
                    int row = r0 + lg * 4 + j;
                    if (col > row) sacc[g][j] = -1e30f;
                }
        }
        // ---- online softmax (base-2) ----
        float ps[4];
#pragma unroll
        for (int j = 0; j < 4; j++) {
            float tv = fmaxf(fmaxf(sacc[0][j], sacc[1][j]), fmaxf(sacc[2][j], sacc[3][j]));
#pragma unroll
            for (int msk = 1; msk < 16; msk <<= 1)
                tv = fmaxf(tv, __shfl_xor(tv, msk, 64));
            float mnew = fmaxf(m_r[j], tv);
            float sc = exp2f(m_r[j] - mnew);
            m_r[j] = mnew;
            l_r[j] *= sc;
#pragma unroll
            for (int g = 0; g < 4; g++) o_acc[g][j] *= sc;
            ps[j] = 0.0f;
        }
#pragma unroll
        for (int g = 0; g < 4; g++)
#pragma unroll
            for (int j = 0; j < 4; j++) {
                float p = exp2f(sacc[g][j] - m_r[j]);
                ps[j] += p;
                Ps[w][(lg * 4 + j) * 72 + g * 16 + lr] = f2bf(p);
            }
#pragma unroll
        for (int j = 0; j < 4; j++) {
            float pv = ps[j];
#pragma unroll
            for (int msk = 1; msk < 16; msk <<= 1)
                pv += __shfl_xor(pv, msk, 64);
            l_r[j] += pv;
        }
        bfrag pf0 = *(const bfrag*)&Ps[w][lr * 72 + lk];
        bfrag pf1 = *(const bfrag*)&Ps[w][lr * 72 + 32 + lk];
        // ---- PV ----
        __builtin_amdgcn_s_setprio(1);
#pragma unroll
        for (int g = 0; g < 4; g++) {
            bfrag vf0 = *(const bfrag*)&Vc[g * 1024 + lr * 64 + swz0];
            bfrag vf1 = *(const bfrag*)&Vc[g * 1024 + lr * 64 + swz1];
            o_acc[g] = __builtin_amdgcn_mfma_f32_16x16x32_bf16(pf0, vf0, o_acc[g], 0, 0, 0);
            o_acc[g] = __builtin_amdgcn_mfma_f32_16x16x32_bf16(pf1, vf1, o_acc[g], 0, 0, 0);
        }
        __builtin_amdgcn_s_setprio(0);
        __syncthreads();
        cur ^= 1;
    }
#undef STAGE

    // ---- fused GroupNorm(D=64) * gate ----
    float gv[4][4];
#pragma unroll
    for (int j = 0; j < 4; j++) {
        const float inv = 1.0f / (l_r[j] + 1e-9f);
#pragma unroll
        for (int g = 0; g < 4; g++) gv[g][j] = o_acc[g][j] * inv;
    }
#pragma unroll
    for (int j = 0; j < 4; j++) {
        float sum = gv[0][j] + gv[1][j] + gv[2][j] + gv[3][j];
#pragma unroll
        for (int msk = 1; msk < 16; msk <<= 1) sum += __shfl_xor(sum, msk, 64);
        const float mu = sum * (1.0f / 64.0f);
        float vs = 0.0f;
#pragma unroll
        for (int g = 0; g < 4; g++) { float dd = gv[g][j] - mu; vs += dd * dd; }
#pragma unroll
        for (int msk = 1; msk < 16; msk <<= 1) vs += __shfl_xor(vs, msk, 64);
        const float rstd = rsqrtf(vs * (1.0f / 64.0f) + 1e-5f);
        const int s = r0 + lg * 4 + j;
#pragma unroll
        for (int g = 0; g < 4; g++) {
            const int col = (h << 6) + g * 16 + lr;
            const float gn = (gv[g][j] - mu) * rstd * gnw[col] + gnb[col];
            const float a = bf2f(alpha[(size_t)s * 2048 + col]);
            gno[(size_t)s * 2048 + col] = f2bf(gn * a);
        }
    }
}

extern "C" void kernel_launch(void* const* d_in, const int* in_sizes, int n_in,
                              void* d_out, int out_size, void* d_ws, size_t ws_size,
                              hipStream_t stream) {
    const float* x   = (const float*)d_in[0];
    const float* rc  = (const float*)d_in[1];
    const float* rs  = (const float*)d_in[2];
    const float* Wq  = (const float*)d_in[3];
    const float* Wk  = (const float*)d_in[4];
    const float* Wv  = (const float*)d_in[5];
    const float* Wo  = (const float*)d_in[6];
    const float* Wg  = (const float*)d_in[7];
    const float* bg  = (const float*)d_in[8];
    const float* gnw = (const float*)d_in[9];
    const float* gnb = (const float*)d_in[10];
    float* out = (float*)d_out;

    char* ws = (char*)d_ws;
    unsigned short* xb    = (unsigned short*)(ws);                      // 8 MB
    unsigned short* WcatT = (unsigned short*)(ws + 8388608);            // 20 MB
    unsigned short* WoT   = (unsigned short*)(ws + 29360128);           // 8 MB
    unsigned short* alpha = (unsigned short*)(ws + 37748736);           // 8 MB
    unsigned short* qb    = (unsigned short*)(ws + 46137344);           // 8 MB
    unsigned short* kbuf  = (unsigned short*)(ws + 54525952);           // 2 MB
    unsigned short* vt    = (unsigned short*)(ws + 56623104);           // 2 MB
    unsigned short* gno   = (unsigned short*)(ws + 58720256);           // 8 MB

    hipLaunchKernelGGL(k_prep, dim3(4608), dim3(256), 0, stream,
                       x, Wq, Wk, Wv, Wg, Wo, xb, WcatT, WoT);

    float* outk = out + (size_t)4 * 1024 * 1024;
    float* outv = out + (size_t)5 * 1024 * 1024;

    hipLaunchKernelGGL(k_gemm_proj, dim3(5120 / 64, 2048 / 128), dim3(256), 0, stream,
                       xb, WcatT, rc, rs, bg, qb, kbuf, vt, alpha, outk, outv);

    hipLaunchKernelGGL(k_attn, dim3(1024), dim3(256), 0, stream,
                       qb, kbuf, vt, alpha, gnw, gnb, gno);

    hipLaunchKernelGGL(k_gemm_out, dim3(2048 / 64, 2048 / 128), dim3(256), 0, stream,
                       gno, WoT, out);
}